// Round 2
// baseline (4089.166 us; speedup 1.0000x reference)
//
#include <hip/hip_runtime.h>

#define N_ROWS 65536
#define DIM    2048
#define EMBD   256
#define NEXP   64
#define BM     64
#define BK     32
#define EPSN   1e-12f
#define TAU    5e-4f
#define CAP    8192
#define RPB    4

__device__ __forceinline__ void top3_insert(float w, int j,
                                            float& v1, int& i1,
                                            float& v2, int& i2,
                                            float& v3, int& i3) {
  // lax.top_k semantics: higher value wins; on exact tie, lower index wins.
  bool b1 = (w > v1) || (w == v1 && j < i1);
  bool b2 = (w > v2) || (w == v2 && j < i2);
  bool b3 = (w > v3) || (w == v3 && j < i3);
  if (b1)      { v3 = v2; i3 = i2; v2 = v1; i2 = i1; v1 = w; i1 = j; }
  else if (b2) { v3 = v2; i3 = i2; v2 = w;  i2 = j; }
  else if (b3) { v3 = w;  i3 = j; }
}

__device__ __forceinline__ void top2_insert_d(double w, int j,
                                              double& v1, int& i1,
                                              double& v2, int& i2) {
  bool b1 = (w > v1) || (w == v1 && j < i1);
  bool b2 = (w > v2) || (w == v2 && j < i2);
  if (b1) { v2 = v1; i2 = i1; v1 = w; i1 = j; }
  else if (b2) { v2 = w; i2 = j; }
}

__global__ __launch_bounds__(256)
void cosine_gating_kernel(const float* __restrict__ x,
                          const float* __restrict__ Wp,
                          const float* __restrict__ emb,
                          const float* __restrict__ temp,
                          float* __restrict__ out,
                          int* __restrict__ ws) {
  __shared__ union Smem {
    struct { float A[BM][44]; float W[BK][260]; } st;
    struct { float P[EMBD][36]; float Eb[32][NEXP]; } ep;
  } sm;
  __shared__ float sEmbInv[NEXP];
  __shared__ float sPart[4][NEXP];

  const int tid = threadIdx.x;
  const int n0  = blockIdx.x * BM;

  // ---- expert-embedding column inverse norms (over EMBD axis) ----
  {
    const int e = tid & 63, part = tid >> 6;
    float s = 0.f;
    #pragma unroll 8
    for (int m = part * 64; m < part * 64 + 64; ++m) {
      float v = emb[m * NEXP + e];
      s += v * v;
    }
    sPart[part][e] = s;
  }
  __syncthreads();
  if (tid < NEXP)
    sEmbInv[tid] = 1.0f / sqrtf(sPart[0][tid] + sPart[1][tid] +
                                sPart[2][tid] + sPart[3][tid] + EPSN);

  // ---- main GEMM: proj = x[n0:n0+BM] @ Wp  (fp32 vector ALU) ----
  const int tc = tid & 15;
  const int tr = tid >> 4;
  float acc[4][16];
  #pragma unroll
  for (int i = 0; i < 4; ++i)
    #pragma unroll
    for (int j = 0; j < 16; ++j) acc[i][j] = 0.f;

  const int arow = tid >> 2;
  const int ac   = (tid & 3) * 8;
  const int wrow = tid >> 3;
  const int wc   = (tid & 7) * 4;
  const float* xp = x + (size_t)(n0 + arow) * DIM + ac;

  for (int k0 = 0; k0 < DIM; k0 += BK) {
    float4 a0 = *(const float4*)(xp + k0);
    float4 a1 = *(const float4*)(xp + k0 + 4);
    float4 wv[8];
    #pragma unroll
    for (int j = 0; j < 8; ++j)
      wv[j] = *(const float4*)(Wp + (size_t)(k0 + wrow) * EMBD + wc + 32 * j);
    __syncthreads();
    *(float4*)&sm.st.A[arow][ac]     = a0;
    *(float4*)&sm.st.A[arow][ac + 4] = a1;
    #pragma unroll
    for (int j = 0; j < 8; ++j)
      *(float4*)&sm.st.W[wrow][wc + 32 * j] = wv[j];
    __syncthreads();
    #pragma unroll
    for (int kk = 0; kk < BK; ++kk) {
      float a[4];
      #pragma unroll
      for (int i = 0; i < 4; ++i) a[i] = sm.st.A[tr * 4 + i][kk];
      #pragma unroll
      for (int q = 0; q < 4; ++q) {
        float4 w = *(const float4*)&sm.st.W[kk][tc * 4 + 64 * q];
        #pragma unroll
        for (int i = 0; i < 4; ++i) {
          acc[i][4*q+0] += a[i] * w.x;
          acc[i][4*q+1] += a[i] * w.y;
          acc[i][4*q+2] += a[i] * w.z;
          acc[i][4*q+3] += a[i] * w.w;
        }
      }
    }
  }

  // ---- row inverse L2 norms ----
  float inv[4];
  #pragma unroll
  for (int i = 0; i < 4; ++i) {
    float s = 0.f;
    #pragma unroll
    for (int j = 0; j < 16; ++j) s += acc[i][j] * acc[i][j];
    #pragma unroll
    for (int off = 8; off >= 1; off >>= 1) s += __shfl_xor(s, off, 16);
    inv[i] = 1.0f / sqrtf(s + EPSN);
  }
  const float T = temp[0];

  float* o_w   = out;
  float* o_idx = out + (size_t)N_ROWS * 64;
  float* o_lg  = o_idx + (size_t)N_ROWS * 2;
  float* o_cos = o_lg + (size_t)N_ROWS * 64;
  float* o_rp  = o_cos + (size_t)N_ROWS * 64;

  const int tc2  = tid & 15;
  const int tr2  = tid >> 4;
  const int r0   = tr2 * 2;
  const int erow = tid >> 3;
  const int ec   = (tid & 7) * 8;

  for (int h = 0; h < 2; ++h) {
    __syncthreads();
    if ((tr >> 3) == h) {
      #pragma unroll
      for (int i = 0; i < 4; ++i) {
        const int rr = (tr & 7) * 4 + i;
        #pragma unroll
        for (int q = 0; q < 4; ++q)
          #pragma unroll
          for (int l = 0; l < 4; ++l)
            sm.ep.P[tc * 4 + 64 * q + l][rr] = acc[i][4 * q + l] * inv[i];
      }
    }
    float c00=0,c01=0,c02=0,c03=0, c10=0,c11=0,c12=0,c13=0;
    for (int mc = 0; mc < 8; ++mc) {
      float4 e0 = *(const float4*)(emb + (size_t)(mc * 32 + erow) * NEXP + ec);
      float4 e1 = *(const float4*)(emb + (size_t)(mc * 32 + erow) * NEXP + ec + 4);
      e0.x *= sEmbInv[ec + 0]; e0.y *= sEmbInv[ec + 1];
      e0.z *= sEmbInv[ec + 2]; e0.w *= sEmbInv[ec + 3];
      e1.x *= sEmbInv[ec + 4]; e1.y *= sEmbInv[ec + 5];
      e1.z *= sEmbInv[ec + 6]; e1.w *= sEmbInv[ec + 7];
      __syncthreads();
      *(float4*)&sm.ep.Eb[erow][ec]     = e0;
      *(float4*)&sm.ep.Eb[erow][ec + 4] = e1;
      __syncthreads();
      #pragma unroll
      for (int mm = 0; mm < 32; ++mm) {
        float2 p  = *(const float2*)&sm.ep.P[mc * 32 + mm][r0];
        float4 ev = *(const float4*)&sm.ep.Eb[mm][tc2 * 4];
        c00 += p.x * ev.x; c01 += p.x * ev.y; c02 += p.x * ev.z; c03 += p.x * ev.w;
        c10 += p.y * ev.x; c11 += p.y * ev.y; c12 += p.y * ev.z; c13 += p.y * ev.w;
      }
    }
    float cs[2][4] = {{c00,c01,c02,c03},{c10,c11,c12,c13}};
    #pragma unroll
    for (int ii = 0; ii < 2; ++ii) {
      float lg[4];
      #pragma unroll
      for (int j = 0; j < 4; ++j) lg[j] = cs[ii][j] * T;
      float v1 = -3.0e38f, v2 = -3.0e38f, v3 = -3.0e38f;
      int   i1 = 1 << 30,  i2 = 1 << 30,  i3 = 1 << 30;
      #pragma unroll
      for (int j = 0; j < 4; ++j)
        top3_insert(lg[j], tc2 * 4 + j, v1, i1, v2, i2, v3, i3);
      #pragma unroll
      for (int off = 1; off < 16; off <<= 1) {
        float w1 = __shfl_xor(v1, off, 16); int j1 = __shfl_xor(i1, off, 16);
        float w2 = __shfl_xor(v2, off, 16); int j2 = __shfl_xor(i2, off, 16);
        float w3 = __shfl_xor(v3, off, 16); int j3 = __shfl_xor(i3, off, 16);
        top3_insert(w1, j1, v1, i1, v2, i2, v3, i3);
        top3_insert(w2, j2, v1, i1, v2, i2, v3, i3);
        top3_insert(w3, j3, v1, i1, v2, i2, v3, i3);
      }
      float ex[4];
      float s = 0.f;
      #pragma unroll
      for (int j = 0; j < 4; ++j) { ex[j] = expf(lg[j] - v1); s += ex[j]; }
      #pragma unroll
      for (int off = 1; off < 16; off <<= 1) s += __shfl_xor(s, off, 16);

      const int n = n0 + 32 * h + r0 + ii;
      const float e21 = expf(v2 - v1);
      const float dm  = 1.0f / (1.0f + e21);
      float wv4[4], rv4[4];
      #pragma unroll
      for (int j = 0; j < 4; ++j) {
        const int e = tc2 * 4 + j;
        wv4[j] = (e == i1) ? dm : ((e == i2) ? e21 * dm : 0.0f);
        rv4[j] = ex[j] / s;
      }
      const size_t ob = (size_t)n * 64 + tc2 * 4;
      *(float4*)&o_w[ob]   = make_float4(wv4[0], wv4[1], wv4[2], wv4[3]);
      *(float4*)&o_lg[ob]  = make_float4(lg[0], lg[1], lg[2], lg[3]);
      *(float4*)&o_cos[ob] = make_float4(cs[ii][0], cs[ii][1], cs[ii][2], cs[ii][3]);
      *(float4*)&o_rp[ob]  = make_float4(rv4[0], rv4[1], rv4[2], rv4[3]);
      if (tc2 == 0) {
        o_idx[(size_t)n * 2]     = (float)i1;
        o_idx[(size_t)n * 2 + 1] = (float)i2;
        // flag near-ties at the rank-1/2 and rank-2/3 boundaries for fp64 refine
        if ((v1 - v2 < TAU) || (v2 - v3 < TAU)) {
          int slot = atomicAdd(&ws[0], 1);
          if (slot < CAP) ws[4 + slot] = n;
        }
      }
    }
  }
}

// fp64 re-computation of flagged rows; overwrites all outputs for those rows.
__global__ __launch_bounds__(256)
void refine_kernel(const float* __restrict__ x,
                   const float* __restrict__ Wp,
                   const float* __restrict__ emb,
                   const float* __restrict__ temp,
                   float* __restrict__ out,
                   const int* __restrict__ ws) {
  __shared__ float  xs[RPB][DIM];       // 32 KB
  __shared__ double projd[RPB][EMBD];   // 8 KB
  __shared__ double embinv[NEXP];
  __shared__ double red[256];

  const int tid = threadIdx.x;
  int cnt = ws[0];
  if (cnt > CAP) cnt = CAP;
  const int base = blockIdx.x * RPB;
  if (base >= cnt) return;
  const int nr = min(RPB, cnt - base);
  int rows[RPB];
  #pragma unroll
  for (int j = 0; j < RPB; ++j) rows[j] = ws[4 + base + (j < nr ? j : 0)];

  // emb column inverse norms in f64
  {
    const int e = tid & 63, part = tid >> 6;
    double s = 0.0;
    for (int m = part * 64; m < part * 64 + 64; ++m) {
      double v = (double)emb[m * NEXP + e];
      s += v * v;
    }
    red[tid] = s;
  }
  __syncthreads();
  if (tid < 64)
    embinv[tid] = 1.0 / sqrt(red[tid] + red[tid + 64] + red[tid + 128] +
                             red[tid + 192] + 1e-12);

  // stage x rows
  for (int j = 0; j < nr; ++j)
    for (int k = tid; k < DIM; k += 256)
      xs[j][k] = x[(size_t)rows[j] * DIM + k];
  __syncthreads();

  // proj columns (thread t -> EMB column t), f64 accumulate
  {
    double s[RPB];
    #pragma unroll
    for (int j = 0; j < RPB; ++j) s[j] = 0.0;
    for (int k = 0; k < DIM; ++k) {
      double w = (double)Wp[(size_t)k * EMBD + tid];
      #pragma unroll
      for (int j = 0; j < RPB; ++j) s[j] += (double)xs[j][k] * w;
    }
    #pragma unroll
    for (int j = 0; j < RPB; ++j) projd[j][tid] = s[j];
  }
  __syncthreads();

  if (tid < 64) {
    float* o_w   = out;
    float* o_idx = out + (size_t)N_ROWS * 64;
    float* o_lg  = o_idx + (size_t)N_ROWS * 2;
    float* o_cos = o_lg + (size_t)N_ROWS * 64;
    float* o_rp  = o_cos + (size_t)N_ROWS * 64;
    const double T = (double)temp[0];
    const int e = tid;
    for (int j = 0; j < nr; ++j) {
      const int row = rows[j];
      double q = 0.0;
      #pragma unroll
      for (int p = 0; p < 4; ++p) {
        double v = projd[j][e + 64 * p];
        q += v * v;
      }
      #pragma unroll
      for (int off = 1; off < 64; off <<= 1) q += __shfl_xor(q, off, 64);
      const double invn = 1.0 / sqrt(q + 1e-12);
      double c = 0.0;
      for (int m = 0; m < EMBD; ++m)
        c += projd[j][m] * (double)emb[m * NEXP + e];
      c *= invn * embinv[e];
      const double lg = c * T;

      double v1 = lg, v2 = -1.0e300;
      int   i1 = e,  i2 = 1 << 30;
      #pragma unroll
      for (int off = 1; off < 64; off <<= 1) {
        double w1 = __shfl_xor(v1, off, 64); int j1 = __shfl_xor(i1, off, 64);
        double w2 = __shfl_xor(v2, off, 64); int j2 = __shfl_xor(i2, off, 64);
        top2_insert_d(w1, j1, v1, i1, v2, i2);
        top2_insert_d(w2, j2, v1, i1, v2, i2);
      }
      const double ex = exp(lg - v1);
      double ssum = ex;
      #pragma unroll
      for (int off = 1; off < 64; off <<= 1) ssum += __shfl_xor(ssum, off, 64);
      const double e21 = exp(v2 - v1);
      const double dm  = 1.0 / (1.0 + e21);

      const size_t ob = (size_t)row * 64 + e;
      o_w[ob]   = (e == i1) ? (float)dm : ((e == i2) ? (float)(e21 * dm) : 0.0f);
      o_lg[ob]  = (float)lg;
      o_cos[ob] = (float)c;
      o_rp[ob]  = (float)(ex / ssum);
      if (e == 0) {
        o_idx[(size_t)row * 2]     = (float)i1;
        o_idx[(size_t)row * 2 + 1] = (float)i2;
      }
    }
  }
}

extern "C" void kernel_launch(void* const* d_in, const int* in_sizes, int n_in,
                              void* d_out, int out_size, void* d_ws, size_t ws_size,
                              hipStream_t stream) {
  const float* x    = (const float*)d_in[0];
  const float* Wp   = (const float*)d_in[1];
  const float* emb  = (const float*)d_in[2];
  const float* temp = (const float*)d_in[3];
  float* out = (float*)d_out;
  int* ws = (int*)d_ws;
  (void)in_sizes; (void)n_in; (void)out_size; (void)ws_size;

  hipMemsetAsync(d_ws, 0, 64, stream);  // zero flagged-row counter
  cosine_gating_kernel<<<dim3(N_ROWS / BM), dim3(256), 0, stream>>>(
      x, Wp, emb, temp, out, ws);
  refine_kernel<<<dim3(CAP / RPB), dim3(256), 0, stream>>>(
      x, Wp, emb, temp, out, ws);
}

// Round 3
// 2173.638 us; speedup vs baseline: 1.8813x; 1.8813x over previous
//
#include <hip/hip_runtime.h>

#define N_ROWS 65536
#define DIM    2048
#define EMBD   256
#define NEXP   64
#define BMAIN  64
#define EPSN   1e-12f
#define TAU    5e-4f
#define CAP    8192
#define RPB    4

// ws layout (bytes): flag counter+list | emb col inv-norms | W frag-pack | emb_n frag-pack
#define WS_EINV   65536
#define WS_WPACK  131072              // 2 limbs x 65536 frags x 16B = 2 MiB
#define WS_EPACK  (131072 + 2097152) // 2 limbs x 2048 frags x 16B = 64 KiB

typedef short short8 __attribute__((ext_vector_type(8)));
typedef float f32x4 __attribute__((ext_vector_type(4)));
typedef unsigned short ushort_t;

__device__ __forceinline__ ushort_t f2bf(float v) {
  unsigned u = __float_as_uint(v);
  u += 0x7fffu + ((u >> 16) & 1u);   // RNE
  return (ushort_t)(u >> 16);
}
__device__ __forceinline__ float bf2f(ushort_t h) {
  return __uint_as_float((unsigned)h << 16);
}

__device__ __forceinline__ void top3_insert(float w, int j,
                                            float& v1, int& i1,
                                            float& v2, int& i2,
                                            float& v3, int& i3) {
  bool b1 = (w > v1) || (w == v1 && j < i1);
  bool b2 = (w > v2) || (w == v2 && j < i2);
  bool b3 = (w > v3) || (w == v3 && j < i3);
  if (b1)      { v3 = v2; i3 = i2; v2 = v1; i2 = i1; v1 = w; i1 = j; }
  else if (b2) { v3 = v2; i3 = i2; v2 = w;  i2 = j; }
  else if (b3) { v3 = w;  i3 = j; }
}

__device__ __forceinline__ void top2_insert_d(double w, int j,
                                              double& v1, int& i1,
                                              double& v2, int& i2) {
  bool b1 = (w > v1) || (w == v1 && j < i1);
  bool b2 = (w > v2) || (w == v2 && j < i2);
  if (b1) { v2 = v1; i2 = i1; v1 = w; i1 = j; }
  else if (b2) { v2 = w; i2 = j; }
}

// ---------------- prep 1: expert-embedding column inverse norms ----------------
__global__ __launch_bounds__(256)
void prep_norms(const float* __restrict__ emb, char* __restrict__ ws) {
  __shared__ float part[4][64];
  const int tid = threadIdx.x;
  const int e = tid & 63, p = tid >> 6;
  float s = 0.f;
  for (int m = p * 64; m < p * 64 + 64; ++m) {
    float v = emb[m * NEXP + e];
    s += v * v;
  }
  part[p][e] = s;
  __syncthreads();
  if (tid < 64) {
    float* einv = (float*)(ws + WS_EINV);
    einv[tid] = 1.0f / sqrtf(part[0][tid] + part[1][tid] + part[2][tid] +
                             part[3][tid] + EPSN);
  }
}

// ---------------- prep 2: pack W and emb_n into MFMA B-fragment order ----------
// B-frag (16x16x32): lane l holds B[k = 32*s + (l>>4)*8 + j][n = 16*t + (l&15)]
__global__ __launch_bounds__(256)
void prep_pack(const float* __restrict__ Wp, const float* __restrict__ emb,
               char* __restrict__ ws) {
  const int gid = blockIdx.x * 256 + threadIdx.x;
  if (blockIdx.x < 256) {
    short8* wH = (short8*)(ws + WS_WPACK);
    short8* wL = wH + 65536;
    const int l = gid & 63, s = (gid >> 6) & 63, t = gid >> 12;
    short8 hv, lv;
    #pragma unroll
    for (int j = 0; j < 8; ++j) {
      float v = Wp[(size_t)(32 * s + ((l >> 4) << 3) + j) * EMBD + 16 * t + (l & 15)];
      ushort_t h = f2bf(v);
      hv[j] = (short)h;
      lv[j] = (short)f2bf(v - bf2f(h));
    }
    wH[(t * 64 + s) * 64 + l] = hv;
    wL[(t * 64 + s) * 64 + l] = lv;
  } else {
    const int g2 = gid - 65536;
    const int l = g2 & 63, s2 = (g2 >> 6) & 7, nt = g2 >> 9;
    const float* einv = (const float*)(ws + WS_EINV);
    short8* eH = (short8*)(ws + WS_EPACK);
    short8* eL = eH + 2048;
    short8 hv, lv;
    #pragma unroll
    for (int j = 0; j < 8; ++j) {
      int k = 32 * s2 + ((l >> 4) << 3) + j;
      int n = 16 * nt + (l & 15);
      float v = emb[k * NEXP + n] * einv[n];
      ushort_t h = f2bf(v);
      hv[j] = (short)h;
      lv[j] = (short)f2bf(v - bf2f(h));
    }
    eH[(nt * 8 + s2) * 64 + l] = hv;
    eL[(nt * 8 + s2) * 64 + l] = lv;
  }
}

// ---------------- main: 64-row tile, bf16 2-limb MFMA GEMM + fused gating ------
__global__ __launch_bounds__(256, 3)
void gate_main(const float* __restrict__ x, const float* __restrict__ temp,
               float* __restrict__ out, char* __restrict__ ws) {
  // A staging & cos buffer union (8.5 KiB) + P frag-pack (32 KiB) + norms
  __shared__ union {
    struct { ushort_t AH[4][64][8]; ushort_t AL[4][64][8]; } a;  // frag-packed A
    float cb[32][68];
  } u;
  __shared__ ushort_t PH[2][8][64][8];  // 16 KiB  [mt2][s2][lane][j]
  __shared__ ushort_t PL[2][8][64][8];  // 16 KiB
  __shared__ float sPart[4][64];
  __shared__ float sInv[64];

  const int tid  = threadIdx.x;
  const int lane = tid & 63;
  const int w    = tid >> 6;
  const int lm   = lane & 15;
  const int lq   = lane >> 4;
  const int n0   = blockIdx.x * BMAIN;

  const short8* wH = (const short8*)(ws + WS_WPACK);
  const short8* wL = wH + 65536;
  const short8* eH = (const short8*)(ws + WS_EPACK);
  const short8* eL = eH + 2048;
  int* flag = (int*)ws;

  f32x4 acc[4][4];
  #pragma unroll
  for (int i = 0; i < 4; ++i)
    #pragma unroll
    for (int j = 0; j < 4; ++j) acc[i][j] = (f32x4){0.f, 0.f, 0.f, 0.f};

  const int arow = tid >> 2;   // 0..63
  const int achk = tid & 3;    // k-chunk 0..3 (8 floats each)
  const float4* xld = (const float4*)(x + (size_t)(n0 + arow) * DIM + achk * 8);
  ushort_t* ah = &u.a.AH[arow >> 4][(arow & 15) + 16 * achk][0];
  ushort_t* al = &u.a.AL[arow >> 4][(arow & 15) + 16 * achk][0];

  for (int s = 0; s < 64; ++s) {
    float4 xa = xld[8 * s];
    float4 xb = xld[8 * s + 1];
    __syncthreads();
    {
      float v[8] = {xa.x, xa.y, xa.z, xa.w, xb.x, xb.y, xb.z, xb.w};
      short8 hv, lv;
      #pragma unroll
      for (int j = 0; j < 8; ++j) {
        ushort_t h = f2bf(v[j]);
        hv[j] = (short)h;
        lv[j] = (short)f2bf(v[j] - bf2f(h));
      }
      *(short8*)ah = hv;
      *(short8*)al = lv;
    }
    __syncthreads();
    short8 Bh[4], Bl[4];
    #pragma unroll
    for (int nt = 0; nt < 4; ++nt) {
      const int t = 4 * w + nt;
      Bh[nt] = wH[(t * 64 + s) * 64 + lane];
      Bl[nt] = wL[(t * 64 + s) * 64 + lane];
    }
    short8 Af[4];
    #pragma unroll
    for (int mt = 0; mt < 4; ++mt) Af[mt] = *(const short8*)&u.a.AH[mt][lane][0];
    #pragma unroll
    for (int mt = 0; mt < 4; ++mt)
      #pragma unroll
      for (int nt = 0; nt < 4; ++nt) {
        acc[mt][nt] = __builtin_amdgcn_mfma_f32_16x16x32_bf16(Af[mt], Bh[nt], acc[mt][nt], 0, 0, 0);
        acc[mt][nt] = __builtin_amdgcn_mfma_f32_16x16x32_bf16(Af[mt], Bl[nt], acc[mt][nt], 0, 0, 0);
      }
    #pragma unroll
    for (int mt = 0; mt < 4; ++mt) Af[mt] = *(const short8*)&u.a.AL[mt][lane][0];
    #pragma unroll
    for (int mt = 0; mt < 4; ++mt)
      #pragma unroll
      for (int nt = 0; nt < 4; ++nt)
        acc[mt][nt] = __builtin_amdgcn_mfma_f32_16x16x32_bf16(Af[mt], Bh[nt], acc[mt][nt], 0, 0, 0);
  }

  // ---- row inverse L2 norms (row = mt*16 + lq*4 + reg, col = w*64 + nt*16 + lm)
  #pragma unroll
  for (int mt = 0; mt < 4; ++mt) {
    #pragma unroll
    for (int reg = 0; reg < 4; ++reg) {
      float ssum = 0.f;
      #pragma unroll
      for (int nt = 0; nt < 4; ++nt) {
        float v = acc[mt][nt][reg];
        ssum += v * v;
      }
      #pragma unroll
      for (int off = 1; off < 16; off <<= 1) ssum += __shfl_xor(ssum, off, 16);
      if (lm == 0) sPart[w][mt * 16 + lq * 4 + reg] = ssum;
    }
  }
  __syncthreads();
  if (tid < 64)
    sInv[tid] = 1.0f / sqrtf(sPart[0][tid] + sPart[1][tid] + sPart[2][tid] +
                             sPart[3][tid] + EPSN);
  __syncthreads();

  const float T = temp[0];
  float* o_w   = out;
  float* o_idx = out + (size_t)N_ROWS * 64;
  float* o_lg  = o_idx + (size_t)N_ROWS * 2;
  float* o_cos = o_lg + (size_t)N_ROWS * 64;
  float* o_rp  = o_cos + (size_t)N_ROWS * 64;

  for (int h = 0; h < 2; ++h) {
    // pack normalized P limbs for rows 32h..32h+31 into A-frag order
    #pragma unroll
    for (int mt = 2 * h; mt < 2 * h + 2; ++mt) {
      #pragma unroll
      for (int nt = 0; nt < 4; ++nt) {
        #pragma unroll
        for (int reg = 0; reg < 4; ++reg) {
          const int row = mt * 16 + lq * 4 + reg;
          const int col = w * 64 + nt * 16 + lm;      // EMB index (GEMM2 K)
          float p = acc[mt][nt][reg] * sInv[row];
          ushort_t hi = f2bf(p);
          ushort_t lo = f2bf(p - bf2f(hi));
          const int rr = row - 32 * h;
          const int li = (rr & 15) + 16 * ((col >> 3) & 3);
          PH[rr >> 4][col >> 5][li][col & 7] = hi;
          PL[rr >> 4][col >> 5][li][col & 7] = lo;
        }
      }
    }
    __syncthreads();
    // GEMM2: cos[32 x 64] = P_n @ emb_n ; wave w -> expert cols 16w..16w+15
    f32x4 a2[2];
    a2[0] = (f32x4){0.f, 0.f, 0.f, 0.f};
    a2[1] = (f32x4){0.f, 0.f, 0.f, 0.f};
    for (int s2 = 0; s2 < 8; ++s2) {
      short8 bh = eH[(w * 8 + s2) * 64 + lane];
      short8 bl = eL[(w * 8 + s2) * 64 + lane];
      #pragma unroll
      for (int m2 = 0; m2 < 2; ++m2) {
        short8 ph = *(const short8*)&PH[m2][s2][lane][0];
        short8 pl = *(const short8*)&PL[m2][s2][lane][0];
        a2[m2] = __builtin_amdgcn_mfma_f32_16x16x32_bf16(ph, bh, a2[m2], 0, 0, 0);
        a2[m2] = __builtin_amdgcn_mfma_f32_16x16x32_bf16(ph, bl, a2[m2], 0, 0, 0);
        a2[m2] = __builtin_amdgcn_mfma_f32_16x16x32_bf16(pl, bh, a2[m2], 0, 0, 0);
      }
    }
    // stage cos into LDS (reuses A-staging union)
    #pragma unroll
    for (int m2 = 0; m2 < 2; ++m2)
      #pragma unroll
      for (int reg = 0; reg < 4; ++reg)
        u.cb[m2 * 16 + lq * 4 + reg][w * 16 + lm] = a2[m2][reg];
    __syncthreads();

    if (tid < 128) {
      const int r  = tid >> 2;   // row within half
      const int qq = tid & 3;    // expert quarter
      float cs[16], lg[16];
      #pragma unroll
      for (int i = 0; i < 4; ++i) {
        float4 cv = *(const float4*)&u.cb[r][16 * qq + 4 * i];
        cs[4*i+0] = cv.x; cs[4*i+1] = cv.y; cs[4*i+2] = cv.z; cs[4*i+3] = cv.w;
      }
      #pragma unroll
      for (int j = 0; j < 16; ++j) lg[j] = cs[j] * T;
      float v1 = -3e38f, v2 = -3e38f, v3 = -3e38f;
      int   i1 = 1 << 30, i2 = 1 << 30, i3 = 1 << 30;
      #pragma unroll
      for (int j = 0; j < 16; ++j)
        top3_insert(lg[j], 16 * qq + j, v1, i1, v2, i2, v3, i3);
      #pragma unroll
      for (int off = 1; off < 4; off <<= 1) {
        float w1 = __shfl_xor(v1, off, 4); int j1 = __shfl_xor(i1, off, 4);
        float w2 = __shfl_xor(v2, off, 4); int j2 = __shfl_xor(i2, off, 4);
        float w3 = __shfl_xor(v3, off, 4); int j3 = __shfl_xor(i3, off, 4);
        top3_insert(w1, j1, v1, i1, v2, i2, v3, i3);
        top3_insert(w2, j2, v1, i1, v2, i2, v3, i3);
        top3_insert(w3, j3, v1, i1, v2, i2, v3, i3);
      }
      float ex[16], ssum = 0.f;
      #pragma unroll
      for (int j = 0; j < 16; ++j) { ex[j] = expf(lg[j] - v1); ssum += ex[j]; }
      #pragma unroll
      for (int off = 1; off < 4; off <<= 1) ssum += __shfl_xor(ssum, off, 4);

      const int n = n0 + 32 * h + r;
      const float e21 = expf(v2 - v1);
      const float dm  = 1.0f / (1.0f + e21);
      const size_t ob = (size_t)n * 64 + 16 * qq;
      #pragma unroll
      for (int i = 0; i < 4; ++i) {
        float t4[4], r4[4];
        #pragma unroll
        for (int jj = 0; jj < 4; ++jj) {
          int e = 16 * qq + 4 * i + jj;
          t4[jj] = (e == i1) ? dm : ((e == i2) ? e21 * dm : 0.f);
          r4[jj] = ex[4 * i + jj] / ssum;
        }
        *(float4*)&o_w[ob + 4 * i]   = make_float4(t4[0], t4[1], t4[2], t4[3]);
        *(float4*)&o_rp[ob + 4 * i]  = make_float4(r4[0], r4[1], r4[2], r4[3]);
        *(float4*)&o_lg[ob + 4 * i]  = make_float4(lg[4*i], lg[4*i+1], lg[4*i+2], lg[4*i+3]);
        *(float4*)&o_cos[ob + 4 * i] = make_float4(cs[4*i], cs[4*i+1], cs[4*i+2], cs[4*i+3]);
      }
      if (qq == 0) {
        o_idx[(size_t)n * 2]     = (float)i1;
        o_idx[(size_t)n * 2 + 1] = (float)i2;
        if ((v1 - v2 < TAU) || (v2 - v3 < TAU)) {
          int slot = atomicAdd(&flag[0], 1);
          if (slot < CAP) flag[4 + slot] = n;
        }
      }
    }
    __syncthreads();
  }
}

// ---------------- fp64 refinement of near-tie rows (unchanged, verified) -------
__global__ __launch_bounds__(256)
void refine_kernel(const float* __restrict__ x,
                   const float* __restrict__ Wp,
                   const float* __restrict__ emb,
                   const float* __restrict__ temp,
                   float* __restrict__ out,
                   const int* __restrict__ ws) {
  __shared__ float  xs[RPB][DIM];
  __shared__ double projd[RPB][EMBD];
  __shared__ double embinv[NEXP];
  __shared__ double red[256];

  const int tid = threadIdx.x;
  int cnt = ws[0];
  if (cnt > CAP) cnt = CAP;
  const int base = blockIdx.x * RPB;
  if (base >= cnt) return;
  const int nr = min(RPB, cnt - base);
  int rows[RPB];
  #pragma unroll
  for (int j = 0; j < RPB; ++j) rows[j] = ws[4 + base + (j < nr ? j : 0)];

  {
    const int e = tid & 63, part = tid >> 6;
    double s = 0.0;
    for (int m = part * 64; m < part * 64 + 64; ++m) {
      double v = (double)emb[m * NEXP + e];
      s += v * v;
    }
    red[tid] = s;
  }
  __syncthreads();
  if (tid < 64)
    embinv[tid] = 1.0 / sqrt(red[tid] + red[tid + 64] + red[tid + 128] +
                             red[tid + 192] + 1e-12);

  for (int j = 0; j < nr; ++j)
    for (int k = tid; k < DIM; k += 256)
      xs[j][k] = x[(size_t)rows[j] * DIM + k];
  __syncthreads();

  {
    double s[RPB];
    #pragma unroll
    for (int j = 0; j < RPB; ++j) s[j] = 0.0;
    for (int k = 0; k < DIM; ++k) {
      double wv = (double)Wp[(size_t)k * EMBD + tid];
      #pragma unroll
      for (int j = 0; j < RPB; ++j) s[j] += (double)xs[j][k] * wv;
    }
    #pragma unroll
    for (int j = 0; j < RPB; ++j) projd[j][tid] = s[j];
  }
  __syncthreads();

  if (tid < 64) {
    float* o_w   = out;
    float* o_idx = out + (size_t)N_ROWS * 64;
    float* o_lg  = o_idx + (size_t)N_ROWS * 2;
    float* o_cos = o_lg + (size_t)N_ROWS * 64;
    float* o_rp  = o_cos + (size_t)N_ROWS * 64;
    const double T = (double)temp[0];
    const int e = tid;
    for (int j = 0; j < nr; ++j) {
      const int row = rows[j];
      double q = 0.0;
      #pragma unroll
      for (int p = 0; p < 4; ++p) {
        double v = projd[j][e + 64 * p];
        q += v * v;
      }
      #pragma unroll
      for (int off = 1; off < 64; off <<= 1) q += __shfl_xor(q, off, 64);
      const double invn = 1.0 / sqrt(q + 1e-12);
      double c = 0.0;
      for (int m = 0; m < EMBD; ++m)
        c += projd[j][m] * (double)emb[m * NEXP + e];
      c *= invn * embinv[e];
      const double lg = c * T;

      double v1 = lg, v2 = -1.0e300;
      int   i1 = e,  i2 = 1 << 30;
      #pragma unroll
      for (int off = 1; off < 64; off <<= 1) {
        double w1 = __shfl_xor(v1, off, 64); int j1 = __shfl_xor(i1, off, 64);
        double w2 = __shfl_xor(v2, off, 64); int j2 = __shfl_xor(i2, off, 64);
        top2_insert_d(w1, j1, v1, i1, v2, i2);
        top2_insert_d(w2, j2, v1, i1, v2, i2);
      }
      const double ex = exp(lg - v1);
      double ssum = ex;
      #pragma unroll
      for (int off = 1; off < 64; off <<= 1) ssum += __shfl_xor(ssum, off, 64);
      const double e21 = exp(v2 - v1);
      const double dm  = 1.0 / (1.0 + e21);

      const size_t ob = (size_t)row * 64 + e;
      o_w[ob]   = (e == i1) ? (float)dm : ((e == i2) ? (float)(e21 * dm) : 0.0f);
      o_lg[ob]  = (float)lg;
      o_cos[ob] = (float)c;
      o_rp[ob]  = (float)(ex / ssum);
      if (e == 0) {
        o_idx[(size_t)row * 2]     = (float)i1;
        o_idx[(size_t)row * 2 + 1] = (float)i2;
      }
    }
  }
}

extern "C" void kernel_launch(void* const* d_in, const int* in_sizes, int n_in,
                              void* d_out, int out_size, void* d_ws, size_t ws_size,
                              hipStream_t stream) {
  const float* x    = (const float*)d_in[0];
  const float* Wp   = (const float*)d_in[1];
  const float* emb  = (const float*)d_in[2];
  const float* temp = (const float*)d_in[3];
  float* out = (float*)d_out;
  char* ws = (char*)d_ws;
  (void)in_sizes; (void)n_in; (void)out_size; (void)ws_size;

  hipMemsetAsync(d_ws, 0, 64, stream);  // zero flagged-row counter
  prep_norms<<<dim3(1), dim3(256), 0, stream>>>(emb, ws);
  prep_pack<<<dim3(264), dim3(256), 0, stream>>>(Wp, emb, ws);
  gate_main<<<dim3(N_ROWS / BMAIN), dim3(256), 0, stream>>>(x, temp, out, ws);
  refine_kernel<<<dim3(CAP / RPB), dim3(256), 0, stream>>>(
      x, Wp, emb, temp, out, (const int*)ws);
}